// Round 5
// baseline (43.126 us; speedup 1.0000x reference)
//
#include <hip/hip_runtime.h>
#include <hip/hip_bf16.h>
#include <stdint.h>

#define NROWS 4096
#define CDIM  512
#define TOPK  5
#define BT    256   // output tile (j and i)
#define BK    32
#define NKT   16    // CDIM / BK

typedef __bf16 bf16x8 __attribute__((ext_vector_type(8)));
typedef float  f32x4  __attribute__((ext_vector_type(4)));
typedef unsigned long long u64;

// 4-slot swizzle: rows 0..15 hit every bank-group exactly twice (2-way = free)
__device__ __forceinline__ int swz(int row) { return (row ^ (row >> 2)) & 3; }

// ---------------- kernel A: prep = bf16 convert (K-tiled + swizzled) + top-5 keys ----
// bf16 layout: o[kt][row][32] with logical 16B slot s stored at s ^ swz(row).
__global__ __launch_bounds__(256) void
prep_kernel(const float* __restrict__ p1, const float* __restrict__ p2,
            const float* __restrict__ feat1,
            __bf16* __restrict__ o1, __bf16* __restrict__ o2,
            u64* __restrict__ keys) {
  const int bid = blockIdx.x, tid = threadIdx.x;
  if (bid < 2048) {
    const int arr = bid >> 10;            // 0: p1->o1, 1: p2->o2
    const int b2  = bid & 1023;
    const int kt  = b2 >> 6;
    const int c   = (b2 & 63) * 256 + tid;  // row*4 + slot
    const int row = c >> 2;
    const int s   = c & 3;
    const float* src = (arr ? p2 : p1) + (size_t)row * CDIM + kt * 32 + s * 8;
    __bf16*      dst = (arr ? o2 : o1) + ((size_t)kt * NROWS + row) * 32 + ((s ^ swz(row)) * 8);
    const float4 a = *(const float4*)src;
    const float4 b = *(const float4*)(src + 4);
    bf16x8 v;
    v[0]=(__bf16)a.x; v[1]=(__bf16)a.y; v[2]=(__bf16)a.z; v[3]=(__bf16)a.w;
    v[4]=(__bf16)b.x; v[5]=(__bf16)b.y; v[6]=(__bf16)b.z; v[7]=(__bf16)b.w;
    *(bf16x8*)dst = v;
  } else {
    const int row = (bid - 2048) * 4 + (tid >> 6);
    const int l   = tid & 63;
    const float* r = feat1 + (size_t)row * CDIM;
    float v[8];
    const float4 a = *(const float4*)(r + l * 8);
    const float4 b = *(const float4*)(r + l * 8 + 4);
    v[0]=a.x; v[1]=a.y; v[2]=a.z; v[3]=a.w;
    v[4]=b.x; v[5]=b.y; v[6]=b.z; v[7]=b.w;

    int sel[TOPK];
#pragma unroll
    for (int s = 0; s < TOPK; ++s) {
      float bv = -__builtin_inff();
      int   bi = 0x7fffffff;
#pragma unroll
      for (int t = 0; t < 8; ++t)
        if (v[t] > bv) { bv = v[t]; bi = l * 8 + t; }   // strict > : smallest idx on tie
#pragma unroll
      for (int off = 32; off > 0; off >>= 1) {
        float ov = __shfl_xor(bv, off);
        int   oi = __shfl_xor(bi, off);
        if (ov > bv || (ov == bv && oi < bi)) { bv = ov; bi = oi; }
      }
      sel[s] = bi;
      const int loc = bi - l * 8;
      if (loc >= 0 && loc < 8) v[loc] = -__builtin_inff();
    }
#define CSWAP(x, y) { int mn = min(sel[x], sel[y]); int mx = max(sel[x], sel[y]); sel[x] = mn; sel[y] = mx; }
    CSWAP(0,1) CSWAP(3,4) CSWAP(2,4) CSWAP(2,3) CSWAP(1,4)
    CSWAP(0,3) CSWAP(0,2) CSWAP(1,3) CSWAP(1,2)
#undef CSWAP
    if (l == 0) {
      keys[row] = (u64)sel[0] | ((u64)sel[1] << 9) | ((u64)sel[2] << 18)
                | ((u64)sel[3] << 27) | ((u64)sel[4] << 36);
    }
  }
}

// ---------------- kernel B: fused GEMM + BCE, 256^2 tile, phased pipeline ----------------
// P[j,i] = dot(prob2[j], prob1[i]). 512 thr = 8 waves (2 j-halves x 4 i-quarters),
// per-wave 128x64 out = acc[8][4]. 4-slot LDS rotation, 2 phases/K-step, counted vmcnt.
__global__ __launch_bounds__(512, 2) void
gemm_loss_kernel(const __bf16* __restrict__ o1k,   // prob1 (i), K-tiled [kt][row][32]
                 const __bf16* __restrict__ o2k,   // prob2 (j), K-tiled
                 const u64* __restrict__ keys,
                 float* __restrict__ partials) {
  __shared__ __bf16 smA[4][BT * BK];   // 4 x 16 KB (prob2 / j rows)
  __shared__ __bf16 smB[4][BT * BK];   // 4 x 16 KB (prob1 / i rows)
  __shared__ float  red[512];

  const int tid = threadIdx.x;
  const int l   = tid & 63, w = tid >> 6;
  const int wr  = w >> 2,  wc = w & 3;     // j-half (0..1), i-quarter (0..3)
  const int lr  = l & 15,  kq = l >> 4;

  // XCD-chunked swizzle: XCD x -> 4 jt x 8 it region: 1MB A + 2MB B < 4MB L2
  const int bid = blockIdx.x;
  const int x   = bid & 7, bv = bid >> 3;  // bv: 0..31
  const int jt  = (x & 3) * 4 + (bv & 3);
  const int it  = (x >> 2) * 8 + (bv >> 2);
  const int jb  = jt * BT, ib = it * BT;

  f32x4 acc[8][4] = {};

  auto stageA = [&](int slot, int kt) {   // 16KB contiguous, 2 loads/thread
    const size_t ko = (size_t)kt * NROWS * 32 + (size_t)jb * 32;
#pragma unroll
    for (int r = 0; r < 2; ++r)
      __builtin_amdgcn_global_load_lds(
          (const __attribute__((address_space(1))) unsigned int*)(const void*)(o2k + ko + (r * 512 + tid) * 8),
          (__attribute__((address_space(3))) unsigned int*)(void*)&smA[slot][(r * 512 + w * 64) * 8], 16, 0, 0);
  };
  auto stageB = [&](int slot, int kt) {
    const size_t ko = (size_t)kt * NROWS * 32 + (size_t)ib * 32;
#pragma unroll
    for (int r = 0; r < 2; ++r)
      __builtin_amdgcn_global_load_lds(
          (const __attribute__((address_space(1))) unsigned int*)(const void*)(o1k + ko + (r * 512 + tid) * 8),
          (__attribute__((address_space(3))) unsigned int*)(void*)&smB[slot][(r * 512 + w * 64) * 8], 16, 0, 0);
  };

  // prologue: slots 0,1 in flight (8 loads); slot0 ready after vmcnt(4)
  stageA(0, 0); stageB(0, 0);
  stageA(1, 1); stageB(1, 1);
  asm volatile("s_waitcnt vmcnt(4)" ::: "memory");
  __builtin_amdgcn_s_barrier();

  for (int kt = 0; kt < NKT; ++kt) {
    const int slot = kt & 3;
    const int nslot = (kt + 2) & 3;
    bf16x8 bfr[4];

    // ---- phase A: B-frags + A m0..3, stage next A, 16 MFMA ----
    {
      bf16x8 af[4];
#pragma unroll
      for (int n = 0; n < 4; ++n) {
        const int r = wc * 64 + n * 16 + lr;
        bfr[n] = *(const bf16x8*)&smB[slot][r * 32 + (kq ^ swz(r)) * 8];
      }
#pragma unroll
      for (int m = 0; m < 4; ++m) {
        const int r = wr * 128 + m * 16 + lr;
        af[m] = *(const bf16x8*)&smA[slot][r * 32 + (kq ^ swz(r)) * 8];
      }
      if (kt + 2 < NKT) stageA(nslot, kt + 2);
      __builtin_amdgcn_s_barrier();
      __builtin_amdgcn_s_setprio(1);
#pragma unroll
      for (int m = 0; m < 4; ++m)
#pragma unroll
        for (int n = 0; n < 4; ++n)
          acc[m][n] = __builtin_amdgcn_mfma_f32_16x16x32_bf16(af[m], bfr[n], acc[m][n], 0, 0, 0);
      __builtin_amdgcn_s_setprio(0);
      __builtin_amdgcn_s_barrier();
    }
    // ---- phase B: A m4..7, stage next B, 16 MFMA, end-of-step vmcnt ----
    {
      bf16x8 af[4];
#pragma unroll
      for (int m = 0; m < 4; ++m) {
        const int r = wr * 128 + (m + 4) * 16 + lr;
        af[m] = *(const bf16x8*)&smA[slot][r * 32 + (kq ^ swz(r)) * 8];
      }
      if (kt + 2 < NKT) stageB(nslot, kt + 2);
      __builtin_amdgcn_s_barrier();
      __builtin_amdgcn_s_setprio(1);
#pragma unroll
      for (int m = 0; m < 4; ++m)
#pragma unroll
        for (int n = 0; n < 4; ++n)
          acc[m + 4][n] = __builtin_amdgcn_mfma_f32_16x16x32_bf16(af[m], bfr[n], acc[m + 4][n], 0, 0, 0);
      __builtin_amdgcn_s_setprio(0);
      if (kt < NKT - 1) {
        if (kt == NKT - 2) asm volatile("s_waitcnt vmcnt(0)" ::: "memory");
        else               asm volatile("s_waitcnt vmcnt(4)" ::: "memory");
        __builtin_amdgcn_s_barrier();
      }
    }
  }

  // ---- epilogue: BCE terms. C/D: col(i) = lane&15, row(j) = (lane>>4)*4 + reg ----
  u64 ki[4];
#pragma unroll
  for (int n = 0; n < 4; ++n)
    ki[n] = keys[ib + wc * 64 + n * 16 + lr];

  float sum = 0.f;
#pragma unroll
  for (int m = 0; m < 8; ++m)
#pragma unroll
    for (int r = 0; r < 4; ++r) {
      const u64 kj = keys[jb + wr * 128 + m * 16 + kq * 4 + r];
#pragma unroll
      for (int n = 0; n < 4; ++n) {
        const float p = acc[m][n][r];
        const bool  t = (kj == ki[n]);
        const float xx = t ? p : (1.0f - p);
        sum += fmaxf(__logf(xx), -100.0f);
      }
    }

  red[tid] = sum;
  __syncthreads();
#pragma unroll
  for (int s = 256; s > 0; s >>= 1) {
    if (tid < s) red[tid] += red[tid + s];
    __syncthreads();
  }
  if (tid == 0) partials[bid] = red[0];
}

// ---------------- kernel C: deterministic finalize ----------------
__global__ void finalize_kernel(const float* __restrict__ partials,
                                float* __restrict__ out) {
  __shared__ float red[256];
  red[threadIdx.x] = partials[threadIdx.x];
  __syncthreads();
  for (int st = 128; st > 0; st >>= 1) {
    if (threadIdx.x < st) red[threadIdx.x] += red[threadIdx.x + st];
    __syncthreads();
  }
  if (threadIdx.x == 0) out[0] = -red[0] * (1.0f / 16777216.0f);
}

extern "C" void kernel_launch(void* const* d_in, const int* in_sizes, int n_in,
                              void* d_out, int out_size, void* d_ws, size_t ws_size,
                              hipStream_t stream) {
  (void)in_sizes; (void)n_in; (void)out_size; (void)ws_size;
  const float* feat1 = (const float*)d_in[0];
  const float* prob1 = (const float*)d_in[2];
  const float* prob2 = (const float*)d_in[3];

  // ws: o1 bf16 (4MB) | o2 bf16 (4MB) | keys (32KB) | partials (1KB)
  __bf16* o1 = (__bf16*)d_ws;
  __bf16* o2 = (__bf16*)((char*)d_ws + (size_t)NROWS * CDIM * 2);
  u64*   keys = (u64*)((char*)d_ws + (size_t)NROWS * CDIM * 4);
  float* partials = (float*)((char*)d_ws + (size_t)NROWS * CDIM * 4 + NROWS * 8);

  prep_kernel<<<3072, 256, 0, stream>>>(prob1, prob2, feat1, o1, o2, keys);
  gemm_loss_kernel<<<256, 512, 0, stream>>>(o1, o2, keys, partials);
  finalize_kernel<<<1, 256, 0, stream>>>(partials, (float*)d_out);
}